// Round 4
// baseline (626.796 us; speedup 1.0000x reference)
//
#include <hip/hip_runtime.h>
#include <math.h>

#define NB 4
#define NT 4096
#define ND 1024
#define NS 16     // NUM_EXPERTS * NUM_SLOTS
#define NE 8
#define NF 4096

__device__ __forceinline__ float gelu(float v) {
  return 0.5f * v * (1.f + erff(v * 0.70710678118654752f));
}
__device__ __forceinline__ void fma4(float4& a, float s, const float4& v) {
  a.x += s * v.x; a.y += s * v.y; a.z += s * v.z; a.w += s * v.w;
}

// ---- zero-fill
__global__ __launch_bounds__(256) void k_zero(float* __restrict__ p, int n) {
  int i = blockIdx.x * 256 + threadIdx.x;
  if (i < n) p[i] = 0.f;
}

// ---- stage A: logits[t][n] = dot(x[t,:], se[n,:]) / 32
// grid 256 blocks x 64 tokens; se in LDS (64KB); wave owns 16 tokens, 4 at a time.
__global__ __launch_bounds__(256) void k_logits(const float* __restrict__ x,
                                                const float* __restrict__ se,
                                                float* __restrict__ logits) {
  __shared__ float s_se[NS * ND];  // [n][d], 64 KB
  for (int i = threadIdx.x; i < NS * ND; i += 256) s_se[i] = se[i];
  __syncthreads();
  const int wave = threadIdx.x >> 6, lane = threadIdx.x & 63;
  const int tbase = blockIdx.x * 64 + wave * 16;
  for (int g = 0; g < 4; ++g) {
    const int t0 = tbase + g * 4;
    float acc[4][NS];
#pragma unroll
    for (int tt = 0; tt < 4; ++tt)
#pragma unroll
      for (int n = 0; n < NS; ++n) acc[tt][n] = 0.f;
#pragma unroll
    for (int it = 0; it < 4; ++it) {
      const int d = it * 256 + lane * 4;
      float4 xv[4];
#pragma unroll
      for (int tt = 0; tt < 4; ++tt)
        xv[tt] = *reinterpret_cast<const float4*>(x + (size_t)(t0 + tt) * ND + d);
#pragma unroll
      for (int n = 0; n < NS; ++n) {
        const float4 sv = *reinterpret_cast<const float4*>(&s_se[n * ND + d]);
#pragma unroll
        for (int tt = 0; tt < 4; ++tt)
          acc[tt][n] += xv[tt].x * sv.x + xv[tt].y * sv.y + xv[tt].z * sv.z + xv[tt].w * sv.w;
      }
    }
#pragma unroll
    for (int tt = 0; tt < 4; ++tt)
#pragma unroll
      for (int n = 0; n < NS; ++n) {
        float v = acc[tt][n];
#pragma unroll
        for (int off = 32; off > 0; off >>= 1) v += __shfl_xor(v, off, 64);
        if (lane == n) logits[(size_t)(t0 + tt) * NS + n] = v * 0.03125f;
      }
  }
}

// ---- stage B: per-(b,n) max & sumexp over T. grid NB*NS, block 256
__global__ __launch_bounds__(256) void k_softmax_stats(const float* __restrict__ logits,
                                                       float* __restrict__ stats) {
  int bn = blockIdx.x;
  int b = bn >> 4, n = bn & 15;
  __shared__ float red[256];
  const float* lp = logits + ((size_t)b * NT) * NS + n;
  float m = -1e30f;
  for (int t = threadIdx.x; t < NT; t += 256) m = fmaxf(m, lp[(size_t)t * NS]);
  red[threadIdx.x] = m; __syncthreads();
  for (int s = 128; s > 0; s >>= 1) {
    if (threadIdx.x < s) red[threadIdx.x] = fmaxf(red[threadIdx.x], red[threadIdx.x + s]);
    __syncthreads();
  }
  m = red[0]; __syncthreads();
  float sm = 0.f;
  for (int t = threadIdx.x; t < NT; t += 256) sm += expf(lp[(size_t)t * NS] - m);
  red[threadIdx.x] = sm; __syncthreads();
  for (int s = 128; s > 0; s >>= 1) {
    if (threadIdx.x < s) red[threadIdx.x] += red[threadIdx.x + s];
    __syncthreads();
  }
  if (threadIdx.x == 0) { stats[bn * 2] = m; stats[bn * 2 + 1] = red[0]; }
}

// ---- stage C: slot_in[b][n][d] += dispatch[b][t][n] * x[b][t][d]
// grid (tc=64, b=4); block covers 64 tokens x full D (thread <-> 4 d's).
__global__ __launch_bounds__(256) void k_slot_in(const float* __restrict__ x,
                                                 const float* __restrict__ logits,
                                                 const float* __restrict__ stats,
                                                 float* __restrict__ slot_in) {
  __shared__ float s_w[64 * NS];
  const int tc = blockIdx.x, b = blockIdx.y;
  const int t0 = tc * 64;
  for (int i = threadIdx.x; i < 64 * NS; i += 256) {
    const int n = i & 15;
    const float m = stats[(b * NS + n) * 2], s = stats[(b * NS + n) * 2 + 1];
    s_w[i] = expf(logits[((size_t)b * NT + t0) * NS + i] - m) / s;
  }
  __syncthreads();
  float4 acc[NS];
#pragma unroll
  for (int n = 0; n < NS; ++n) acc[n] = make_float4(0.f, 0.f, 0.f, 0.f);
  const int d = threadIdx.x * 4;
  for (int t = 0; t < 64; ++t) {
    const float4 xv = *reinterpret_cast<const float4*>(x + ((size_t)b * NT + t0 + t) * ND + d);
#pragma unroll
    for (int n = 0; n < NS; ++n) fma4(acc[n], s_w[t * NS + n], xv);
  }
#pragma unroll
  for (int n = 0; n < NS; ++n) {
    float* dst = slot_in + ((size_t)b * NS + n) * ND + d;
    atomicAdd(dst + 0, acc[n].x); atomicAdd(dst + 1, acc[n].y);
    atomicAdd(dst + 2, acc[n].z); atomicAdd(dst + 3, acc[n].w);
  }
}

// ---- stage D: LayerNorm over D, IN-PLACE. grid NB*NS rows, block 256
__global__ __launch_bounds__(256) void k_layernorm(float* __restrict__ slot_in,
                                                   const float* __restrict__ gamma,
                                                   const float* __restrict__ beta) {
  int row = blockIdx.x;
  __shared__ float red[256];
  float* rp = slot_in + (size_t)row * ND;
  float v[4];
  float sum = 0.f;
#pragma unroll
  for (int j = 0; j < 4; ++j) { v[j] = rp[threadIdx.x + j * 256]; sum += v[j]; }
  red[threadIdx.x] = sum; __syncthreads();
  for (int s = 128; s > 0; s >>= 1) {
    if (threadIdx.x < s) red[threadIdx.x] += red[threadIdx.x + s];
    __syncthreads();
  }
  float mu = red[0] * (1.f / ND); __syncthreads();
  float vs = 0.f;
#pragma unroll
  for (int j = 0; j < 4; ++j) { float t = v[j] - mu; vs += t * t; }
  red[threadIdx.x] = vs; __syncthreads();
  for (int s = 128; s > 0; s >>= 1) {
    if (threadIdx.x < s) red[threadIdx.x] += red[threadIdx.x + s];
    __syncthreads();
  }
  float rstd = rsqrtf(red[0] * (1.f / ND) + 1e-5f);
#pragma unroll
  for (int j = 0; j < 4; ++j) {
    int dd = threadIdx.x + j * 256;
    rp[dd] = (v[j] - mu) * rstd * gamma[dd] + beta[dd];
  }
}

// ---- stage E: u[b,e,s,f] += h[b,e,s,:] @ W1[e,:,f]
// grid (ft=4, dc=16, e=8) = 512 blocks; thread <-> 4 f's (float4 W1 loads).
__global__ __launch_bounds__(256) void k_mlp1(const float* __restrict__ h,
                                              const float* __restrict__ W1,
                                              float* __restrict__ u) {
  __shared__ float s_h[64][8];  // [dd][j], j = b*2+s
  const int ft = blockIdx.x, dc = blockIdx.y, e = blockIdx.z;
  for (int i = threadIdx.x; i < 512; i += 256) {
    const int dd = i >> 3, j = i & 7;
    const int b = j >> 1, s = j & 1;
    s_h[dd][j] = h[((size_t)b * NS + e * 2 + s) * ND + dc * 64 + dd];
  }
  __syncthreads();
  float4 acc[8];
#pragma unroll
  for (int j = 0; j < 8; ++j) acc[j] = make_float4(0.f, 0.f, 0.f, 0.f);
  const int f = ft * 1024 + threadIdx.x * 4;
  const float* wbase = W1 + (size_t)(e * ND + dc * 64) * NF + f;
  for (int dd = 0; dd < 64; ++dd) {
    const float4 wv = *reinterpret_cast<const float4*>(wbase + (size_t)dd * NF);
    const float4 h0 = *reinterpret_cast<const float4*>(&s_h[dd][0]);
    const float4 h1 = *reinterpret_cast<const float4*>(&s_h[dd][4]);
    fma4(acc[0], h0.x, wv); fma4(acc[1], h0.y, wv);
    fma4(acc[2], h0.z, wv); fma4(acc[3], h0.w, wv);
    fma4(acc[4], h1.x, wv); fma4(acc[5], h1.y, wv);
    fma4(acc[6], h1.z, wv); fma4(acc[7], h1.w, wv);
  }
#pragma unroll
  for (int j = 0; j < 8; ++j) {
    const int b = j >> 1, s = j & 1;
    float* dst = u + ((size_t)(b * NE + e) * 2 + s) * NF + f;
    atomicAdd(dst + 0, acc[j].x); atomicAdd(dst + 1, acc[j].y);
    atomicAdd(dst + 2, acc[j].z); atomicAdd(dst + 3, acc[j].w);
  }
}

// ---- stage F: slot_out[b,n,d] += gelu(u[b,e,s,:]) @ W2[e,:,d]
// grid (fc=64, e=8) = 512 blocks; thread <-> 4 d's (float4 W2 loads).
__global__ __launch_bounds__(256) void k_mlp2(const float* __restrict__ u,
                                              const float* __restrict__ W2,
                                              float* __restrict__ slot_out) {
  __shared__ float s_u[64][8];  // [ff][j]
  const int fc = blockIdx.x, e = blockIdx.y;
  for (int i = threadIdx.x; i < 512; i += 256) {
    const int ff = i >> 3, j = i & 7;
    const int b = j >> 1, s = j & 1;
    s_u[ff][j] = gelu(u[((size_t)(b * NE + e) * 2 + s) * NF + fc * 64 + ff]);
  }
  __syncthreads();
  float4 acc[8];
#pragma unroll
  for (int j = 0; j < 8; ++j) acc[j] = make_float4(0.f, 0.f, 0.f, 0.f);
  const int d = threadIdx.x * 4;
  const float* wbase = W2 + ((size_t)e * NF + fc * 64) * ND + d;
  for (int ff = 0; ff < 64; ++ff) {
    const float4 wv = *reinterpret_cast<const float4*>(wbase + (size_t)ff * ND);
    const float4 u0 = *reinterpret_cast<const float4*>(&s_u[ff][0]);
    const float4 u1 = *reinterpret_cast<const float4*>(&s_u[ff][4]);
    fma4(acc[0], u0.x, wv); fma4(acc[1], u0.y, wv);
    fma4(acc[2], u0.z, wv); fma4(acc[3], u0.w, wv);
    fma4(acc[4], u1.x, wv); fma4(acc[5], u1.y, wv);
    fma4(acc[6], u1.z, wv); fma4(acc[7], u1.w, wv);
  }
#pragma unroll
  for (int j = 0; j < 8; ++j) {
    const int b = j >> 1, s = j & 1;
    float* dst = slot_out + ((size_t)b * NS + e * 2 + s) * ND + d;
    atomicAdd(dst + 0, acc[j].x); atomicAdd(dst + 1, acc[j].y);
    atomicAdd(dst + 2, acc[j].z); atomicAdd(dst + 3, acc[j].w);
  }
}

// ---- stage G: combine softmax over 16 slots + weighted sum.
// grid (tb=64, b=4); slot_out[b] staged in LDS (64KB); wave owns 16 tokens, 4 at a time.
__global__ __launch_bounds__(256) void k_combine(const float* __restrict__ logits,
                                                 const float* __restrict__ slot_out,
                                                 float* __restrict__ out) {
  __shared__ float s_so[NS * ND];  // [n][d], 64 KB
  const int tb = blockIdx.x, b = blockIdx.y;
  for (int i = threadIdx.x; i < NS * ND; i += 256)
    s_so[i] = slot_out[(size_t)b * NS * ND + i];
  __syncthreads();
  const int wave = threadIdx.x >> 6, lane = threadIdx.x & 63;
  const int tbase = tb * 64 + wave * 16;
  for (int g = 0; g < 4; ++g) {
    const int t0 = tbase + g * 4;  // token within batch
    float c[4][NS];
#pragma unroll
    for (int tt = 0; tt < 4; ++tt) {
      const float* lp = logits + ((size_t)b * NT + t0 + tt) * NS;
      float l[NS];
      float m = -1e30f;
#pragma unroll
      for (int n = 0; n < NS; ++n) { l[n] = lp[n]; m = fmaxf(m, l[n]); }
      float s = 0.f;
#pragma unroll
      for (int n = 0; n < NS; ++n) { l[n] = expf(l[n] - m); s += l[n]; }
      const float rs = 1.f / s;
#pragma unroll
      for (int n = 0; n < NS; ++n) c[tt][n] = l[n] * rs;
    }
#pragma unroll
    for (int it = 0; it < 4; ++it) {
      const int d = it * 256 + lane * 4;
      float4 acc[4];
#pragma unroll
      for (int tt = 0; tt < 4; ++tt) acc[tt] = make_float4(0.f, 0.f, 0.f, 0.f);
#pragma unroll
      for (int n = 0; n < NS; ++n) {
        const float4 sv = *reinterpret_cast<const float4*>(&s_so[n * ND + d]);
        fma4(acc[0], c[0][n], sv); fma4(acc[1], c[1][n], sv);
        fma4(acc[2], c[2][n], sv); fma4(acc[3], c[3][n], sv);
      }
#pragma unroll
      for (int tt = 0; tt < 4; ++tt)
        *reinterpret_cast<float4*>(out + ((size_t)b * NT + t0 + tt) * ND + d) = acc[tt];
    }
  }
}

extern "C" void kernel_launch(void* const* d_in, const int* in_sizes, int n_in,
                              void* d_out, int out_size, void* d_ws, size_t ws_size,
                              hipStream_t stream) {
  const float* x     = (const float*)d_in[0];
  const float* se    = (const float*)d_in[1];
  const float* W1    = (const float*)d_in[2];
  const float* W2    = (const float*)d_in[3];
  const float* gamma = (const float*)d_in[4];
  const float* beta  = (const float*)d_in[5];
  float* out = (float*)d_out;

  // workspace layout (floats), total 655,616 f32 = 2.62 MB
  float* ws       = (float*)d_ws;
  float* logits   = ws;                 // 262144
  float* stats    = ws + 262144;        // 128 (padded to 256)
  float* slot_in  = ws + 262400;        // 65536  (becomes h in-place after LN)
  float* slot_out = ws + 327936;        // 65536
  float* u        = ws + 393472;        // 262144

  // zero slot_in + slot_out + u (contiguous, 393216 floats)
  k_zero<<<1536, 256, 0, stream>>>(slot_in, 393216);

  k_logits<<<256, 256, 0, stream>>>(x, se, logits);
  k_softmax_stats<<<NB * NS, 256, 0, stream>>>(logits, stats);
  k_slot_in<<<dim3(64, NB), 256, 0, stream>>>(x, logits, stats, slot_in);
  k_layernorm<<<NB * NS, 256, 0, stream>>>(slot_in, gamma, beta);
  k_mlp1<<<dim3(4, 16, NE), 256, 0, stream>>>(slot_in, W1, u);
  k_mlp2<<<dim3(64, NE), 256, 0, stream>>>(u, W2, slot_out);
  k_combine<<<dim3(64, NB), 256, 0, stream>>>(logits, slot_out, out);
}

// Round 5
// 475.291 us; speedup vs baseline: 1.3188x; 1.3188x over previous
//
#include <hip/hip_runtime.h>
#include <math.h>

#define NB 4
#define NT 4096
#define ND 1024
#define NS 16     // NUM_EXPERTS * NUM_SLOTS
#define NE 8
#define NF 4096

__device__ __forceinline__ float gelu(float v) {
  return 0.5f * v * (1.f + erff(v * 0.70710678118654752f));
}
__device__ __forceinline__ void fma4(float4& a, float s, const float4& v) {
  a.x += s * v.x; a.y += s * v.y; a.z += s * v.z; a.w += s * v.w;
}
__device__ __forceinline__ float4 ld4(const float* p) {
  return *reinterpret_cast<const float4*>(p);
}

// ---- stage A: logits[t][n] = dot(x[t,:], se[n,:]) / 32
// grid 256 blocks x 64 tokens; se in LDS (64KB); wave owns 16 tokens, 4 at a time.
__global__ __launch_bounds__(256) void k_logits(const float* __restrict__ x,
                                                const float* __restrict__ se,
                                                float* __restrict__ logits) {
  __shared__ float s_se[NS * ND];  // [n][d], 64 KB
  for (int i = threadIdx.x; i < NS * ND; i += 256) s_se[i] = se[i];
  __syncthreads();
  const int wave = threadIdx.x >> 6, lane = threadIdx.x & 63;
  const int tbase = blockIdx.x * 64 + wave * 16;
  for (int g = 0; g < 4; ++g) {
    const int t0 = tbase + g * 4;
    float acc[4][NS];
#pragma unroll
    for (int tt = 0; tt < 4; ++tt)
#pragma unroll
      for (int n = 0; n < NS; ++n) acc[tt][n] = 0.f;
#pragma unroll
    for (int it = 0; it < 4; ++it) {
      const int d = it * 256 + lane * 4;
      float4 xv[4];
#pragma unroll
      for (int tt = 0; tt < 4; ++tt)
        xv[tt] = ld4(x + (size_t)(t0 + tt) * ND + d);
#pragma unroll
      for (int n = 0; n < NS; ++n) {
        const float4 sv = ld4(&s_se[n * ND + d]);
#pragma unroll
        for (int tt = 0; tt < 4; ++tt)
          acc[tt][n] += xv[tt].x * sv.x + xv[tt].y * sv.y + xv[tt].z * sv.z + xv[tt].w * sv.w;
      }
    }
#pragma unroll
    for (int tt = 0; tt < 4; ++tt)
#pragma unroll
      for (int n = 0; n < NS; ++n) {
        float v = acc[tt][n];
#pragma unroll
        for (int off = 32; off > 0; off >>= 1) v += __shfl_xor(v, off, 64);
        if (lane == n) logits[(size_t)(t0 + tt) * NS + n] = v * 0.03125f;
      }
  }
}

// ---- stage B: per-(b,n) max & sumexp over T. grid NB*NS, block 256
__global__ __launch_bounds__(256) void k_softmax_stats(const float* __restrict__ logits,
                                                       float* __restrict__ stats) {
  int bn = blockIdx.x;
  int b = bn >> 4, n = bn & 15;
  __shared__ float red[256];
  const float* lp = logits + ((size_t)b * NT) * NS + n;
  float m = -1e30f;
  for (int t = threadIdx.x; t < NT; t += 256) m = fmaxf(m, lp[(size_t)t * NS]);
  red[threadIdx.x] = m; __syncthreads();
  for (int s = 128; s > 0; s >>= 1) {
    if (threadIdx.x < s) red[threadIdx.x] = fmaxf(red[threadIdx.x], red[threadIdx.x + s]);
    __syncthreads();
  }
  m = red[0]; __syncthreads();
  float sm = 0.f;
  for (int t = threadIdx.x; t < NT; t += 256) sm += expf(lp[(size_t)t * NS] - m);
  red[threadIdx.x] = sm; __syncthreads();
  for (int s = 128; s > 0; s >>= 1) {
    if (threadIdx.x < s) red[threadIdx.x] += red[threadIdx.x + s];
    __syncthreads();
  }
  if (threadIdx.x == 0) { stats[bn * 2] = m; stats[bn * 2 + 1] = red[0]; }
}

// ---- stage C: si_part[tc][b][n][d] = sum_{t in tc} dispatch[b][t][n] * x[b][t][d]
// grid (tc=64, b=4) = 256 blocks; thread <-> 4 d's; NO atomics (private partials).
__global__ __launch_bounds__(256) void k_slot_in(const float* __restrict__ x,
                                                 const float* __restrict__ logits,
                                                 const float* __restrict__ stats,
                                                 float* __restrict__ si_part) {
  __shared__ float s_w[NS][64];  // [n][t] so inner loop reads float4 over t
  const int tc = blockIdx.x, b = blockIdx.y;
  const int t0 = tc * 64;
  for (int i = threadIdx.x; i < NS * 64; i += 256) {
    const int n = i >> 6, t = i & 63;
    const float m = stats[(b * NS + n) * 2], s1 = stats[(b * NS + n) * 2 + 1];
    s_w[n][t] = expf(logits[((size_t)b * NT + t0 + t) * NS + n] - m) / s1;
  }
  __syncthreads();
  float4 acc[NS];
#pragma unroll
  for (int n = 0; n < NS; ++n) acc[n] = make_float4(0.f, 0.f, 0.f, 0.f);
  const int d = threadIdx.x * 4;
  for (int t = 0; t < 64; t += 4) {
    float4 xv[4];
#pragma unroll
    for (int k = 0; k < 4; ++k)
      xv[k] = ld4(x + ((size_t)b * NT + t0 + t + k) * ND + d);
#pragma unroll
    for (int n = 0; n < NS; ++n) {
      const float4 wn = ld4(&s_w[n][t]);
      fma4(acc[n], wn.x, xv[0]); fma4(acc[n], wn.y, xv[1]);
      fma4(acc[n], wn.z, xv[2]); fma4(acc[n], wn.w, xv[3]);
    }
  }
#pragma unroll
  for (int n = 0; n < NS; ++n)
    *reinterpret_cast<float4*>(si_part + (((size_t)tc * 4 + b) * NS + n) * ND + d) = acc[n];
}

// ---- stage C2: slot_in[row][d] = sum_tc si_part[tc][row][d]. grid 256, block 256
__global__ __launch_bounds__(256) void k_reduce_si(const float* __restrict__ si_part,
                                                   float* __restrict__ slot_in) {
  const int i = blockIdx.x * 256 + threadIdx.x;  // i in [0, 65536)
  const int row = i >> 10, d = i & 1023;         // row = b*16+n
  const int b = row >> 4, n = row & 15;
  float sum = 0.f;
  for (int tc = 0; tc < 64; ++tc)
    sum += si_part[(((size_t)tc * 4 + b) * NS + n) * ND + d];
  slot_in[i] = sum;
}

// ---- stage D: LayerNorm over D, IN-PLACE. grid NB*NS rows, block 256
__global__ __launch_bounds__(256) void k_layernorm(float* __restrict__ slot_in,
                                                   const float* __restrict__ gamma,
                                                   const float* __restrict__ beta) {
  int row = blockIdx.x;
  __shared__ float red[256];
  float* rp = slot_in + (size_t)row * ND;
  float v[4];
  float sum = 0.f;
#pragma unroll
  for (int j = 0; j < 4; ++j) { v[j] = rp[threadIdx.x + j * 256]; sum += v[j]; }
  red[threadIdx.x] = sum; __syncthreads();
  for (int s = 128; s > 0; s >>= 1) {
    if (threadIdx.x < s) red[threadIdx.x] += red[threadIdx.x + s];
    __syncthreads();
  }
  float mu = red[0] * (1.f / ND); __syncthreads();
  float vs = 0.f;
#pragma unroll
  for (int j = 0; j < 4; ++j) { float t = v[j] - mu; vs += t * t; }
  red[threadIdx.x] = vs; __syncthreads();
  for (int s = 128; s > 0; s >>= 1) {
    if (threadIdx.x < s) red[threadIdx.x] += red[threadIdx.x + s];
    __syncthreads();
  }
  float rstd = rsqrtf(red[0] * (1.f / ND) + 1e-5f);
#pragma unroll
  for (int j = 0; j < 4; ++j) {
    int dd = threadIdx.x + j * 256;
    rp[dd] = (v[j] - mu) * rstd * gamma[dd] + beta[dd];
  }
}

// ---- stage E: u_part[dc][row][f] = h[row-chunk] @ W1-chunk (row=(b*NE+e)*2+s)
// grid (ft=4, dc=16, e=8) = 512 blocks; thread <-> 4 f's; K=64, unroll 4.
__global__ __launch_bounds__(256) void k_mlp1(const float* __restrict__ h,
                                              const float* __restrict__ W1,
                                              float* __restrict__ u_part) {
  __shared__ float s_h[64][8];  // [dd][j], j = b*2+s
  const int ft = blockIdx.x, dc = blockIdx.y, e = blockIdx.z;
  for (int i = threadIdx.x; i < 512; i += 256) {
    const int dd = i >> 3, j = i & 7;
    const int b = j >> 1, s = j & 1;
    s_h[dd][j] = h[((size_t)b * NS + e * 2 + s) * ND + dc * 64 + dd];
  }
  __syncthreads();
  float4 acc[8];
#pragma unroll
  for (int j = 0; j < 8; ++j) acc[j] = make_float4(0.f, 0.f, 0.f, 0.f);
  const int f = ft * 1024 + threadIdx.x * 4;
  const float* wbase = W1 + ((size_t)e * ND + dc * 64) * NF + f;
  for (int dd = 0; dd < 64; dd += 4) {
    float4 wv[4];
#pragma unroll
    for (int k = 0; k < 4; ++k)
      wv[k] = ld4(wbase + (size_t)(dd + k) * NF);
#pragma unroll
    for (int k = 0; k < 4; ++k) {
      const float4 h0 = ld4(&s_h[dd + k][0]);
      const float4 h1 = ld4(&s_h[dd + k][4]);
      fma4(acc[0], h0.x, wv[k]); fma4(acc[1], h0.y, wv[k]);
      fma4(acc[2], h0.z, wv[k]); fma4(acc[3], h0.w, wv[k]);
      fma4(acc[4], h1.x, wv[k]); fma4(acc[5], h1.y, wv[k]);
      fma4(acc[6], h1.z, wv[k]); fma4(acc[7], h1.w, wv[k]);
    }
  }
#pragma unroll
  for (int j = 0; j < 8; ++j) {
    const int b = j >> 1, s = j & 1;
    const size_t row = ((size_t)b * NE + e) * 2 + s;
    *reinterpret_cast<float4*>(u_part + ((size_t)dc * 64 + row) * NF + f) = acc[j];
  }
}

// ---- stage E2: u[i] = gelu(sum_dc u_part[dc][i]). grid 1024, block 256
__global__ __launch_bounds__(256) void k_reduce_gelu(const float* __restrict__ u_part,
                                                     float* __restrict__ u) {
  const int i = blockIdx.x * 256 + threadIdx.x;  // [0, 262144)
  float sum = 0.f;
  for (int dc = 0; dc < 16; ++dc)
    sum += u_part[(size_t)dc * 262144 + i];
  u[i] = gelu(sum);
}

// ---- stage F: so_part[fc][row][d] = gelu_u-chunk @ W2-chunk (row = b*16+e*2+s)
// grid (fc=64, e=8) = 512 blocks; thread <-> 4 d's; K=64, unroll 4.
__global__ __launch_bounds__(256) void k_mlp2(const float* __restrict__ u,
                                              const float* __restrict__ W2,
                                              float* __restrict__ so_part) {
  __shared__ float s_u[64][8];  // [ff][j]
  const int fc = blockIdx.x, e = blockIdx.y;
  for (int i = threadIdx.x; i < 512; i += 256) {
    const int ff = i >> 3, j = i & 7;
    const int b = j >> 1, s = j & 1;
    s_u[ff][j] = u[(((size_t)b * NE + e) * 2 + s) * NF + fc * 64 + ff];
  }
  __syncthreads();
  float4 acc[8];
#pragma unroll
  for (int j = 0; j < 8; ++j) acc[j] = make_float4(0.f, 0.f, 0.f, 0.f);
  const int d = threadIdx.x * 4;
  const float* wbase = W2 + ((size_t)e * NF + fc * 64) * ND + d;
  for (int ff = 0; ff < 64; ff += 4) {
    float4 wv[4];
#pragma unroll
    for (int k = 0; k < 4; ++k)
      wv[k] = ld4(wbase + (size_t)(ff + k) * ND);
#pragma unroll
    for (int k = 0; k < 4; ++k) {
      const float4 u0 = ld4(&s_u[ff + k][0]);
      const float4 u1 = ld4(&s_u[ff + k][4]);
      fma4(acc[0], u0.x, wv[k]); fma4(acc[1], u0.y, wv[k]);
      fma4(acc[2], u0.z, wv[k]); fma4(acc[3], u0.w, wv[k]);
      fma4(acc[4], u1.x, wv[k]); fma4(acc[5], u1.y, wv[k]);
      fma4(acc[6], u1.z, wv[k]); fma4(acc[7], u1.w, wv[k]);
    }
  }
#pragma unroll
  for (int j = 0; j < 8; ++j) {
    const int b = j >> 1, s = j & 1;
    const size_t row = (size_t)b * NS + e * 2 + s;
    *reinterpret_cast<float4*>(so_part + ((size_t)fc * 64 + row) * ND + d) = acc[j];
  }
}

// ---- stage F2: slot_out[i] = sum_fc so_part[fc][i]. grid 256, block 256
__global__ __launch_bounds__(256) void k_reduce_so(const float* __restrict__ so_part,
                                                   float* __restrict__ slot_out) {
  const int i = blockIdx.x * 256 + threadIdx.x;  // [0, 65536)
  float sum = 0.f;
  for (int fc = 0; fc < 64; ++fc)
    sum += so_part[(size_t)fc * 65536 + i];
  slot_out[i] = sum;
}

// ---- stage G: combine softmax over 16 slots + weighted sum.
// grid (tb=64, b=4); slot_out[b] staged in LDS (64KB); wave owns 16 tokens, 4 at a time.
__global__ __launch_bounds__(256) void k_combine(const float* __restrict__ logits,
                                                 const float* __restrict__ slot_out,
                                                 float* __restrict__ out) {
  __shared__ float s_so[NS * ND];  // [n][d], 64 KB
  const int tb = blockIdx.x, b = blockIdx.y;
  for (int i = threadIdx.x; i < NS * ND; i += 256)
    s_so[i] = slot_out[(size_t)b * NS * ND + i];
  __syncthreads();
  const int wave = threadIdx.x >> 6, lane = threadIdx.x & 63;
  const int tbase = tb * 64 + wave * 16;
  for (int g = 0; g < 4; ++g) {
    const int t0 = tbase + g * 4;  // token within batch
    float c[4][NS];
#pragma unroll
    for (int tt = 0; tt < 4; ++tt) {
      const float* lp = logits + ((size_t)b * NT + t0 + tt) * NS;
      float l[NS];
      float m = -1e30f;
#pragma unroll
      for (int n = 0; n < NS; ++n) { l[n] = lp[n]; m = fmaxf(m, l[n]); }
      float s = 0.f;
#pragma unroll
      for (int n = 0; n < NS; ++n) { l[n] = expf(l[n] - m); s += l[n]; }
      const float rs = 1.f / s;
#pragma unroll
      for (int n = 0; n < NS; ++n) c[tt][n] = l[n] * rs;
    }
#pragma unroll
    for (int it = 0; it < 4; ++it) {
      const int d = it * 256 + lane * 4;
      float4 acc[4];
#pragma unroll
      for (int tt = 0; tt < 4; ++tt) acc[tt] = make_float4(0.f, 0.f, 0.f, 0.f);
#pragma unroll
      for (int n = 0; n < NS; ++n) {
        const float4 sv = ld4(&s_so[n * ND + d]);
        fma4(acc[0], c[0][n], sv); fma4(acc[1], c[1][n], sv);
        fma4(acc[2], c[2][n], sv); fma4(acc[3], c[3][n], sv);
      }
#pragma unroll
      for (int tt = 0; tt < 4; ++tt)
        *reinterpret_cast<float4*>(out + ((size_t)b * NT + t0 + tt) * ND + d) = acc[tt];
    }
  }
}

extern "C" void kernel_launch(void* const* d_in, const int* in_sizes, int n_in,
                              void* d_out, int out_size, void* d_ws, size_t ws_size,
                              hipStream_t stream) {
  const float* x     = (const float*)d_in[0];
  const float* se    = (const float*)d_in[1];
  const float* W1    = (const float*)d_in[2];
  const float* W2    = (const float*)d_in[3];
  const float* gamma = (const float*)d_in[4];
  const float* beta  = (const float*)d_in[5];
  float* out = (float*)d_out;

  // workspace layout (floats); everything fully written before read -> no zeroing.
  float* ws       = (float*)d_ws;
  float* logits   = ws;                   // 262,144          (1 MB)
  float* stats    = ws + 262144;          // 128 (pad 256)
  float* slot_in  = ws + 262400;          // 65,536           (becomes h after LN)
  float* slot_out = ws + 327936;          // 65,536
  float* u        = ws + 393472;          // 262,144
  float* si_part  = ws + 655616;          // 4,194,304        (16 MB)
  float* u_part   = ws + 4849920;         // 4,194,304        (16 MB)
  float* so_part  = ws + 9044224;         // 4,194,304        (16 MB)

  k_logits<<<256, 256, 0, stream>>>(x, se, logits);
  k_softmax_stats<<<NB * NS, 256, 0, stream>>>(logits, stats);
  k_slot_in<<<dim3(64, NB), 256, 0, stream>>>(x, logits, stats, si_part);
  k_reduce_si<<<256, 256, 0, stream>>>(si_part, slot_in);
  k_layernorm<<<NB * NS, 256, 0, stream>>>(slot_in, gamma, beta);
  k_mlp1<<<dim3(4, 16, NE), 256, 0, stream>>>(slot_in, W1, u_part);
  k_reduce_gelu<<<1024, 256, 0, stream>>>(u_part, u);
  k_mlp2<<<dim3(64, NE), 256, 0, stream>>>(u, W2, so_part);
  k_reduce_so<<<256, 256, 0, stream>>>(so_part, slot_out);
  k_combine<<<dim3(64, NB), 256, 0, stream>>>(logits, slot_out, out);
}